// Round 8
// baseline (446.185 us; speedup 1.0000x reference)
//
#include <hip/hip_runtime.h>
#include <hip/hip_fp16.h>

#define N_NODES 100000
#define N_EDGES 3200000
#define N_GRAPHS 64
#define IN_DIM 128
#define HIDDEN 64
#define LATENT 16

#define NC 256          // coarse buckets (512 nodes each), node>>9
#define CSHIFT 9
#define NBC_USED ((N_NODES + 511) / 512)   // 196
#define SC_BLOCKS 128   // blocks for hist/scatter
#define FINE_CAP 20000  // LDS edge stage cap (mean 16384, sigma~127 -> 28 sigma)

// ---------------- tiny zero kernel ----------------
__global__ __launch_bounds__(256) void zero_k(int4* __restrict__ p, int n4) {
  int i = blockIdx.x * 256 + threadIdx.x;
  if (i < n4) p[i] = make_int4(0, 0, 0, 0);
}

// ---------------- pass A: coarse histograms (256 buckets); dump per-block counts ----
__global__ __launch_bounds__(256) void hist_c_k(const int4* __restrict__ src4,
                                                const int4* __restrict__ dst4,
                                                int* __restrict__ bc_src,
                                                int* __restrict__ bc_dst,
                                                int* __restrict__ tbl_src,
                                                int* __restrict__ tbl_dst) {
  __shared__ int hs[NC], hd[NC];
  int t = threadIdx.x;
  if (t < NC) { hs[t] = 0; hd[t] = 0; }
  __syncthreads();
  const int Q = N_EDGES / 4;            // 800000
  const int QPB = Q / SC_BLOCKS;        // 6250
  int q0 = blockIdx.x * QPB, q1 = q0 + QPB;
  for (int i = q0 + t; i < q1; i += 256) {
    int4 s = src4[i], d = dst4[i];
    atomicAdd(&hs[s.x >> CSHIFT], 1); atomicAdd(&hs[s.y >> CSHIFT], 1);
    atomicAdd(&hs[s.z >> CSHIFT], 1); atomicAdd(&hs[s.w >> CSHIFT], 1);
    atomicAdd(&hd[d.x >> CSHIFT], 1); atomicAdd(&hd[d.y >> CSHIFT], 1);
    atomicAdd(&hd[d.z >> CSHIFT], 1); atomicAdd(&hd[d.w >> CSHIFT], 1);
  }
  __syncthreads();
  if (t < NC) {
    int a = hs[t], b = hd[t];
    tbl_src[blockIdx.x * NC + t] = a;
    tbl_dst[blockIdx.x * NC + t] = b;
    if (a) atomicAdd(&bc_src[t], a);
    if (b) atomicAdd(&bc_dst[t], b);
  }
}

// ---------------- pass B: exclusive scan of both 256-entry count arrays ----------------
__global__ __launch_bounds__(256) void scan_c_k(const int* __restrict__ bc_src,
                                                const int* __restrict__ bc_dst,
                                                int* __restrict__ bbase_src,
                                                int* __restrict__ bbase_dst,
                                                int* __restrict__ row_ptr) {
  __shared__ int a[NC], b[NC];
  int t = threadIdx.x;
  int va = bc_src[t], vb = bc_dst[t];
  a[t] = va; b[t] = vb;
  __syncthreads();
  for (int off = 1; off < NC; off <<= 1) {
    int xa = 0, xb = 0;
    if (t >= off) { xa = a[t - off]; xb = b[t - off]; }
    __syncthreads();
    if (t >= off) { a[t] += xa; b[t] += xb; }
    __syncthreads();
  }
  bbase_src[t] = a[t] - va;
  bbase_dst[t] = b[t] - vb;
  if (t == NC - 1) {
    bbase_src[NC] = a[t];
    bbase_dst[NC] = b[t];
    row_ptr[N_NODES] = N_EDGES;
  }
}

// ---------------- pass C: coarse scatter (runs ~98 edges/bucket -> ~1.2x write amp) ----
__global__ __launch_bounds__(256) void scatter_c_k(const int4* __restrict__ src4,
                                                   const int4* __restrict__ dst4,
                                                   const int* __restrict__ bbase_src,
                                                   const int* __restrict__ bbase_dst,
                                                   const int* __restrict__ tbl_src,
                                                   const int* __restrict__ tbl_dst,
                                                   int* __restrict__ cur_src,
                                                   int* __restrict__ cur_dst,
                                                   int* __restrict__ sortedS,
                                                   int* __restrict__ sortedE) {
  __shared__ int rs[NC], rd[NC];
  int t = threadIdx.x;
  if (t < NC) {
    int a = tbl_src[blockIdx.x * NC + t];
    int b = tbl_dst[blockIdx.x * NC + t];
    rs[t] = a ? (atomicAdd(&cur_src[t], a) + bbase_src[t]) : 0;
    rd[t] = b ? (atomicAdd(&cur_dst[t], b) + bbase_dst[t]) : 0;
  }
  __syncthreads();
  const int Q = N_EDGES / 4;
  const int QPB = Q / SC_BLOCKS;
  int q0 = blockIdx.x * QPB, q1 = q0 + QPB;
  for (int i = q0 + t; i < q1; i += 256) {
    int4 s = src4[i], d = dst4[i];
    int sv[4] = {s.x, s.y, s.z, s.w};
    int dv[4] = {d.x, d.y, d.z, d.w};
#pragma unroll
    for (int k = 0; k < 4; k++) {
      int ps = atomicAdd(&rs[sv[k] >> CSHIFT], 1);
      sortedS[ps] = sv[k];
      int pd = atomicAdd(&rd[dv[k] >> CSHIFT], 1);
      sortedE[pd] = ((dv[k] & 511) << 17) | sv[k];
    }
  }
}

// ---------------- pass D: fine CSR per coarse dst-bucket (edges staged in LDS) ----------
__global__ __launch_bounds__(256) void fine_csr_k(const int* __restrict__ sortedE,
                                                  const int* __restrict__ bbase_dst,
                                                  int* __restrict__ deg_in,
                                                  int* __restrict__ row_ptr,
                                                  int* __restrict__ csr_src) {
  __shared__ int edges[FINE_CAP];
  __shared__ int hin[512], scn[512], cur[512];
  __shared__ int ts[256];
  int bk = blockIdx.x, t = threadIdx.x;
  int node0 = bk << CSHIFT;
  int e0 = bbase_dst[bk], e1 = bbase_dst[bk + 1];
  int m = e1 - e0;
  bool fits = (m <= FINE_CAP);
  if (t < 256) { }  // no-op
  hin[t] = 0; hin[t + 256] = 0;
  cur[t] = 0; cur[t + 256] = 0;
  __syncthreads();
  // load + hist (stage to LDS when it fits)
  for (int j = e0 + t; j < e1; j += 256) {
    int v = sortedE[j];
    if (fits) edges[j - e0] = v;
    atomicAdd(&hin[v >> 17], 1);
  }
  __syncthreads();
  // exclusive scan over 512 node counts (2/thread)
  int v0 = hin[2 * t], v1 = hin[2 * t + 1];
  int tot = v0 + v1;
  ts[t] = tot;
  __syncthreads();
  for (int off = 1; off < 256; off <<= 1) {
    int x = 0;
    if (t >= off) x = ts[t - off];
    __syncthreads();
    if (t >= off) ts[t] += x;
    __syncthreads();
  }
  int base = ts[t] - tot;
  scn[2 * t] = base;
  scn[2 * t + 1] = base + v0;
  __syncthreads();
  // write degrees + row_ptr (coalesced, 2 nodes/thread)
#pragma unroll
  for (int k = 0; k < 2; k++) {
    int l = 2 * t + k;
    int n = node0 + l;
    if (n < N_NODES) {
      deg_in[n] = hin[l];
      row_ptr[n] = e0 + scn[l];
    }
  }
  __syncthreads();
  // scatter csr in node order within block-private output region
  for (int j = e0 + t; j < e1; j += 256) {
    int v = fits ? edges[j - e0] : sortedE[j];
    int ln = v >> 17;
    int pos = e0 + scn[ln] + atomicAdd(&cur[ln], 1);
    csr_src[pos] = v & 0x1FFFF;
  }
}

// ---------------- deg_out: per coarse src-bucket LDS hist over sortedS ----------------
__global__ __launch_bounds__(256) void degout_c_k(const int* __restrict__ sortedS,
                                                  const int* __restrict__ bbase_src,
                                                  int* __restrict__ deg_out) {
  __shared__ int h[512];
  int bk = blockIdx.x, t = threadIdx.x;
  h[t] = 0; h[t + 256] = 0;
  __syncthreads();
  int s0 = bbase_src[bk], s1 = bbase_src[bk + 1];
  for (int j = s0 + t; j < s1; j += 256) atomicAdd(&h[sortedS[j] & 511], 1);
  __syncthreads();
#pragma unroll
  for (int k = 0; k < 2; k++) {
    int l = 2 * t + k;
    int n = (bk << CSHIFT) + l;
    if (n < N_NODES) deg_out[n] = h[l];
  }
}

// ---------------- register-tiled GEMM: out[n][c] = (X@W)[n][c] * rsqrt(max(deg,1)) ----
template <int IN, typename IT, typename OT>
__global__ __launch_bounds__(256) void gemm_tile_k(const IT* __restrict__ X,
                                                   const float* __restrict__ W,
                                                   const int* __restrict__ deg,
                                                   OT* __restrict__ out) {
  __shared__ float xs[64][IN + 4];
  __shared__ float ws[IN][HIDDEN];
  int t = threadIdx.x;
  int row0_blk = blockIdx.x * 64;

  for (int i = t; i < IN * HIDDEN / 4; i += 256)
    ((float4*)ws)[i] = ((const float4*)W)[i];
  for (int i = t; i < 64 * (IN / 4); i += 256) {
    int r = i / (IN / 4), c4 = i % (IN / 4);
    int row = row0_blk + r;
    float4 v = make_float4(0.f, 0.f, 0.f, 0.f);
    if (row < N_NODES) {
      if constexpr (sizeof(IT) == 4) {
        v = *(const float4*)&X[(size_t)row * IN + c4 * 4];
      } else {
        union { short4 s; __half2 h2[2]; } u;
        u.s = *(const short4*)&X[(size_t)row * IN + c4 * 4];
        float2 f0 = __half22float2(u.h2[0]);
        float2 f1 = __half22float2(u.h2[1]);
        v = make_float4(f0.x, f0.y, f1.x, f1.y);
      }
    }
    *(float4*)&xs[r][c4 * 4] = v;
  }
  __syncthreads();

  int w = t >> 6, lane = t & 63;
  int rg = lane >> 4, cg = lane & 15;
  int r0 = w * 16 + rg * 4;
  int c0 = cg * 4;

  float acc[4][4];
#pragma unroll
  for (int i = 0; i < 4; i++)
#pragma unroll
    for (int j = 0; j < 4; j++) acc[i][j] = 0.f;

#pragma unroll 4
  for (int d4 = 0; d4 < IN / 4; d4++) {
    float4 a0 = *(const float4*)&xs[r0 + 0][d4 * 4];
    float4 a1 = *(const float4*)&xs[r0 + 1][d4 * 4];
    float4 a2 = *(const float4*)&xs[r0 + 2][d4 * 4];
    float4 a3 = *(const float4*)&xs[r0 + 3][d4 * 4];
#pragma unroll
    for (int dd = 0; dd < 4; dd++) {
      float4 b = *(const float4*)&ws[d4 * 4 + dd][c0];
      float av0 = (&a0.x)[dd], av1 = (&a1.x)[dd], av2 = (&a2.x)[dd], av3 = (&a3.x)[dd];
      acc[0][0] += av0 * b.x; acc[0][1] += av0 * b.y; acc[0][2] += av0 * b.z; acc[0][3] += av0 * b.w;
      acc[1][0] += av1 * b.x; acc[1][1] += av1 * b.y; acc[1][2] += av1 * b.z; acc[1][3] += av1 * b.w;
      acc[2][0] += av2 * b.x; acc[2][1] += av2 * b.y; acc[2][2] += av2 * b.z; acc[2][3] += av2 * b.w;
      acc[3][0] += av3 * b.x; acc[3][1] += av3 * b.y; acc[3][2] += av3 * b.z; acc[3][3] += av3 * b.w;
    }
  }

#pragma unroll
  for (int i = 0; i < 4; i++) {
    int row = row0_blk + r0 + i;
    if (row >= N_NODES) continue;
    float dg = (float)deg[row];
    if (dg < 1.f) dg = 1.f;
    float sc = rsqrtf(dg);
    if constexpr (sizeof(OT) == 2) {
      __half2 p0 = __floats2half2_rn(acc[i][0] * sc, acc[i][1] * sc);
      __half2 p1 = __floats2half2_rn(acc[i][2] * sc, acc[i][3] * sc);
      union { __half2 h2[2]; float2 f2; } u;
      u.h2[0] = p0; u.h2[1] = p1;
      *(float2*)&out[(size_t)row * HIDDEN + c0] = u.f2;
    } else {
      float4 o = make_float4(acc[i][0] * sc, acc[i][1] * sc, acc[i][2] * sc, acc[i][3] * sc);
      *(float4*)&out[(size_t)row * HIDDEN + c0] = o;
    }
  }
}

// ---------------- aggregate (fp16 gather, fp32 regs, fp16 out) ----------------
__global__ __launch_bounds__(256) void aggregate_k(const __half* __restrict__ hw,
                                                   const int* __restrict__ row_ptr,
                                                   const int* __restrict__ csr_src,
                                                   const int* __restrict__ deg_in,
                                                   const float* __restrict__ bias,
                                                   __half* __restrict__ out) {
  int wave = (int)((blockIdx.x * blockDim.x + threadIdx.x) >> 6);
  int lane = threadIdx.x & 63;
  if (wave >= N_NODES) return;
  int start = row_ptr[wave], end = row_ptr[wave + 1];
  float acc = 0.f;
  int j = start;
  for (; j + 15 < end; j += 16) {
    int idx[16];
#pragma unroll
    for (int k = 0; k < 16; k++) idx[k] = csr_src[j + k];
    float a[16];
#pragma unroll
    for (int k = 0; k < 16; k++) a[k] = __half2float(hw[(size_t)idx[k] * HIDDEN + lane]);
    float s01 = (a[0] + a[1]) + (a[2] + a[3]);
    float s23 = (a[4] + a[5]) + (a[6] + a[7]);
    float s45 = (a[8] + a[9]) + (a[10] + a[11]);
    float s67 = (a[12] + a[13]) + (a[14] + a[15]);
    acc += (s01 + s23) + (s45 + s67);
  }
  for (; j + 7 < end; j += 8) {
    int idx[8];
#pragma unroll
    for (int k = 0; k < 8; k++) idx[k] = csr_src[j + k];
    float a[8];
#pragma unroll
    for (int k = 0; k < 8; k++) a[k] = __half2float(hw[(size_t)idx[k] * HIDDEN + lane]);
    acc += ((a[0] + a[1]) + (a[2] + a[3])) + ((a[4] + a[5]) + (a[6] + a[7]));
  }
  for (; j < end; j++) {
    int s = csr_src[j];
    acc += __half2float(hw[(size_t)s * HIDDEN + lane]);
  }
  float dg = (float)deg_in[wave];
  if (dg < 1.f) dg = 1.f;
  float v = acc * rsqrtf(dg) + bias[lane];
  out[(size_t)wave * HIDDEN + lane] = __float2half(v > 0.f ? v : 0.f);
}

// ---------------- per-graph mean pool (sorted node_graph, run-accumulate) ----------------
__global__ __launch_bounds__(256) void pool_k(const __half* __restrict__ h,
                                              const int* __restrict__ node_graph,
                                              float* __restrict__ sums,
                                              float* __restrict__ counts) {
  const int NPW = 256;  // nodes per wave
  int wave = (int)((blockIdx.x * blockDim.x + threadIdx.x) >> 6);
  int lane = threadIdx.x & 63;
  int start = wave * NPW;
  if (start >= N_NODES) return;
  int end = start + NPW; if (end > N_NODES) end = N_NODES;
  int cur = node_graph[start];
  float acc = 0.f, cnt = 0.f;
  for (int n = start; n < end; n++) {
    int g = node_graph[n];
    if (g != cur) {
      atomicAdd(&sums[cur * HIDDEN + lane], acc);
      if (lane == 0) atomicAdd(&counts[cur], cnt);
      cur = g; acc = 0.f; cnt = 0.f;
    }
    acc += __half2float(h[(size_t)n * HIDDEN + lane]);
    cnt += 1.f;
  }
  atomicAdd(&sums[cur * HIDDEN + lane], acc);
  if (lane == 0) atomicAdd(&counts[cur], cnt);
}

// ---------------- final: h_graph = sums/counts; mu/logvar = h_graph @ Wmu/Wlv + b ----------------
__global__ __launch_bounds__(256) void final_k(const float* __restrict__ sums,
                                               const float* __restrict__ counts,
                                               const float* __restrict__ Wmu,
                                               const float* __restrict__ bmu,
                                               const float* __restrict__ Wlv,
                                               const float* __restrict__ blv,
                                               float* __restrict__ out) {
  __shared__ float hg[N_GRAPHS][HIDDEN];
  __shared__ float wmu[HIDDEN][LATENT];
  __shared__ float wlv[HIDDEN][LATENT];
  int t = threadIdx.x;
  for (int i = t; i < N_GRAPHS * HIDDEN; i += 256) {
    int g = i / HIDDEN;
    float c = counts[g];
    if (c < 1.f) c = 1.f;
    hg[g][i % HIDDEN] = sums[i] / c;
  }
  for (int i = t; i < HIDDEN * LATENT; i += 256) {
    wmu[i / LATENT][i % LATENT] = Wmu[i];
    wlv[i / LATENT][i % LATENT] = Wlv[i];
  }
  __syncthreads();
  for (int i = t; i < N_GRAPHS * LATENT; i += 256) {
    int g = i / LATENT, j = i % LATENT;
    float mu = bmu[j], lv = blv[j];
#pragma unroll
    for (int k = 0; k < HIDDEN; k++) {
      float v = hg[g][k];
      mu += v * wmu[k][j];
      lv += v * wlv[k][j];
    }
    out[i] = mu;
    out[N_GRAPHS * LATENT + i] = lv;
  }
}

extern "C" void kernel_launch(void* const* d_in, const int* in_sizes, int n_in,
                              void* d_out, int out_size, void* d_ws, size_t ws_size,
                              hipStream_t stream) {
  const float* x = (const float*)d_in[0];
  // d_in[1] = edge_feat: provably unused for (mu, logvar)
  const int* src = (const int*)d_in[2];
  const int* dst = (const int*)d_in[3];
  const int* node_graph = (const int*)d_in[4];
  const float* W1 = (const float*)d_in[5];
  const float* b1 = (const float*)d_in[6];
  const float* W2 = (const float*)d_in[7];
  const float* b2 = (const float*)d_in[8];
  // d_in[9] = We, d_in[10] = be: unused
  const float* Wmu = (const float*)d_in[11];
  const float* bmu = (const float*)d_in[12];
  const float* Wlv = (const float*)d_in[13];
  const float* blv = (const float*)d_in[14];
  float* out = (float*)d_out;

  char* ws = (char*)d_ws;
  // zeroed control block [0, 20992)
  int* bc_src   = (int*)(ws + 0);        // 1024
  int* bc_dst   = (int*)(ws + 1024);     // 1024
  int* cur_src  = (int*)(ws + 2048);     // 1024
  int* cur_dst  = (int*)(ws + 3072);     // 1024
  float* cnts   = (float*)(ws + 4096);   // 512
  float* sums   = (float*)(ws + 4608);   // 16384 -> 20992
  // non-zeroed control
  int* bbase_src = (int*)(ws + 21504);   // 1028 (pad)
  int* bbase_dst = (int*)(ws + 22784);   // 1028 (pad)
  int* tbl_src   = (int*)(ws + 24576);   // 131072
  int* tbl_dst   = (int*)(ws + 155648);  // 131072 -> 286720
  // big arrays
  int* deg_out = (int*)(ws + 286720);    // 400128
  int* deg_in  = (int*)(ws + 686848);    // 400128
  int* row_ptr = (int*)(ws + 1086976);   // 400128 -> 1487104
  int* csr_src = (int*)(ws + 1487104);   // 12800000 -> 14287104
  int* sortedS = (int*)(ws + 14287104);  // 12800000 -> 27087104 (dead after degout)
  int* sortedE = (int*)(ws + 27087104);  // 12800000 -> 39887104 (dead after fine_csr)
  __half* A    = (__half*)(ws + 14287104); // alias of sortedS
  __half* B    = (__half*)(ws + 27087104); // alias of sortedE

  zero_k<<<(20992 / 16 + 255) / 256, 256, 0, stream>>>((int4*)ws, 20992 / 16);

  hist_c_k<<<SC_BLOCKS, 256, 0, stream>>>((const int4*)src, (const int4*)dst,
                                          bc_src, bc_dst, tbl_src, tbl_dst);
  scan_c_k<<<1, 256, 0, stream>>>(bc_src, bc_dst, bbase_src, bbase_dst, row_ptr);
  scatter_c_k<<<SC_BLOCKS, 256, 0, stream>>>((const int4*)src, (const int4*)dst,
                                             bbase_src, bbase_dst, tbl_src, tbl_dst,
                                             cur_src, cur_dst, sortedS, sortedE);
  fine_csr_k<<<NBC_USED, 256, 0, stream>>>(sortedE, bbase_dst, deg_in, row_ptr, csr_src);
  degout_c_k<<<NBC_USED, 256, 0, stream>>>(sortedS, bbase_src, deg_out);

  const int GEMM_BLKS = (N_NODES + 63) / 64;  // 1563

  // layer 1: A = fp16((x @ W1) * deg_out^-1/2) ; B = fp16(relu(agg(A)*deg_in^-1/2 + b1))
  gemm_tile_k<IN_DIM, float, __half><<<GEMM_BLKS, 256, 0, stream>>>(x, W1, deg_out, A);
  aggregate_k<<<(N_NODES + 3) / 4, 256, 0, stream>>>(A, row_ptr, csr_src, deg_in, b1, B);

  // layer 2: A = fp16((B @ W2) * deg_out^-1/2) ; B = fp16(relu(agg(A)*deg_in^-1/2 + b2))
  gemm_tile_k<HIDDEN, __half, __half><<<GEMM_BLKS, 256, 0, stream>>>(B, W2, deg_out, A);
  aggregate_k<<<(N_NODES + 3) / 4, 256, 0, stream>>>(A, row_ptr, csr_src, deg_in, b2, B);

  // pool + heads
  pool_k<<<((N_NODES + 255) / 256 + 3) / 4, 256, 0, stream>>>(B, node_graph, sums, cnts);
  final_k<<<1, 256, 0, stream>>>(sums, cnts, Wmu, bmu, Wlv, blv, out);
}